// Round 1
// baseline (3795.137 us; speedup 1.0000x reference)
//
#include <hip/hip_runtime.h>
#include <math.h>

#define BB 256
#define CC 64
#define TS 2048
#define HH 64
#define TT 64

// LDS float offsets
#define XT0 0
#define XT1 4096
#define H0O 8192
#define H1O 8256
#define RZ0 8320
#define RZ1 8448
#define SCRO 8576
#define LDSF 8768

__device__ __forceinline__ float sigmoidf_(float v){ return 1.0f/(1.0f+__expf(-v)); }
__device__ __forceinline__ float tanhf_(float v){
  v = fminf(15.0f, fmaxf(-15.0f, v));
  float e = __expf(2.0f*v);
  return (e-1.0f)/(e+1.0f);
}

__global__ __launch_bounds__(512, 2)
void gru_attn_fused(const float* __restrict__ x,
                    const float* __restrict__ w_ih0, const float* __restrict__ w_hh0,
                    const float* __restrict__ b_ih0, const float* __restrict__ b_hh0,
                    const float* __restrict__ w_ih1, const float* __restrict__ w_hh1,
                    const float* __restrict__ b_ih1, const float* __restrict__ b_hh1,
                    const float* __restrict__ attn_w1, const float* __restrict__ attn_b1,
                    const float* __restrict__ attn_w2, const float* __restrict__ attn_b2,
                    const float* __restrict__ ln_g, const float* __restrict__ ln_b,
                    const float* __restrict__ head_w1, const float* __restrict__ head_b1,
                    const float* __restrict__ head_w2, const float* __restrict__ head_b2,
                    float* __restrict__ out)
{
  __shared__ float lds[LDSF];
  const int tid  = threadIdx.x;
  const int b    = blockIdx.x;
  const int wid  = tid >> 6;
  const int lane = tid & 63;
  const bool isGate = (wid < 6);
  const bool isAttn = (wid == 6);
  const int  l   = (wid < 3) ? 0 : 1;        // gate-wave layer
  const int  g   = isGate ? (tid - l*192) : 0; // gate row 0..191 (r:0-63, z:64-127, n:128-191)
  const float* xb = x + (size_t)b * CC * TS;

  // Role-overloaded register arrays:
  //   gate waves: wA = w_ih row, wB = w_hh row
  //   attn wave : wA = attn_w1 row
  //   stage wave: wB[0..3] = x prefetch pipeline
  float4 wA[16], wB[16];
  float bi = 0.f, bh = 0.f, w2j = 0.f, b2v = 0.f;

  if (isGate) {
    const float* wih = ((l==0) ? w_ih0 : w_ih1) + g*64;
    const float* whh = ((l==0) ? w_hh0 : w_hh1) + g*64;
    #pragma unroll
    for (int i=0;i<16;i++){ wA[i] = ((const float4*)wih)[i]; wB[i] = ((const float4*)whh)[i]; }
    bi = ((l==0) ? b_ih0 : b_ih1)[g];
    bh = ((l==0) ? b_hh0 : b_hh1)[g];
  } else if (isAttn) {
    const float* aw = attn_w1 + lane*64;
    #pragma unroll
    for (int i=0;i<16;i++){ wA[i] = ((const float4*)aw)[i]; }
    bi  = attn_b1[lane];
    w2j = attn_w2[lane];
    b2v = attn_b2[0];
  }

  // zero h0, h1, rz0, rz1 (contiguous 384 floats at H0O)
  if (tid < 384) lds[H0O + tid] = 0.f;

  // stage x tile 0 (transposed: xT[tt][c]), all threads cooperate
  {
    const int c0 = tid >> 3;
    const int q  = tid & 7;
    const int t0 = q*8;
    #pragma unroll
    for (int m=0;m<2;m++){
      float4 v = *(const float4*)(xb + c0*TS + t0 + m*4);
      lds[XT0 + (t0+m*4+0)*64 + c0] = v.x;
      lds[XT0 + (t0+m*4+1)*64 + c0] = v.y;
      lds[XT0 + (t0+m*4+2)*64 + c0] = v.z;
      lds[XT0 + (t0+m*4+3)*64 + c0] = v.w;
    }
  }
  __syncthreads();

  float am = -1e30f, aZ = 0.f, aP = 0.f;   // online softmax state (attn wave)
  float xnk = 0.f, hnk = 0.f;              // n-gate carries A->B

  // Skewed pipeline: iter i: L0@t=i, L1@t=i-1, attn@t=i-2
  #pragma unroll 1
  for (int it = 0; it < TS + 2; ++it) {
    const int tt   = it & (TT-1);
    const int tile = it >> 6;
    const int xsel = tile & 1;

    // ---------------- phase A ----------------
    if (isGate) {
      const bool act = (l==0) ? (it < TS) : (it >= 1 && it <= TS);
      if (act) {
        const float* iv = (l==0) ? &lds[(xsel ? XT1 : XT0) + tt*64] : &lds[H0O];
        const float* hv = (l==0) ? &lds[H0O] : &lds[H1O];
        float a0=0,a1=0,a2=0,a3=0, c0=0,c1=0,c2=0,c3=0;
        #pragma unroll
        for (int i=0;i<16;i++){
          const float4 vx = ((const float4*)iv)[i];
          const float4 vh = ((const float4*)hv)[i];
          a0 = fmaf(wA[i].x, vx.x, a0);
          a1 = fmaf(wA[i].y, vx.y, a1);
          a2 = fmaf(wA[i].z, vx.z, a2);
          a3 = fmaf(wA[i].w, vx.w, a3);
          c0 = fmaf(wB[i].x, vh.x, c0);
          c1 = fmaf(wB[i].y, vh.y, c1);
          c2 = fmaf(wB[i].z, vh.z, c2);
          c3 = fmaf(wB[i].w, vh.w, c3);
        }
        const float ihd = bi + ((a0+a1)+(a2+a3));
        const float hhd = bh + ((c0+c1)+(c2+c3));
        if (g < 128) {
          lds[((l==0)?RZ0:RZ1) + g] = sigmoidf_(ihd + hhd);
        } else {
          xnk = ihd; hnk = hhd;   // n-gate: keep xn, hn separate (r*(hn+b_hh) semantics)
        }
      }
    } else if (isAttn) {
      if (it >= 2) {
        const float* hv = &lds[H1O];
        float a0=0,a1=0,a2=0,a3=0;
        #pragma unroll
        for (int i=0;i<16;i++){
          const float4 vh = ((const float4*)hv)[i];
          a0 = fmaf(wA[i].x, vh.x, a0);
          a1 = fmaf(wA[i].y, vh.y, a1);
          a2 = fmaf(wA[i].z, vh.z, a2);
          a3 = fmaf(wA[i].w, vh.w, a3);
        }
        float av = tanhf_(bi + ((a0+a1)+(a2+a3)));
        float sp = w2j * av;
        #pragma unroll
        for (int m=1;m<64;m<<=1) sp += __shfl_xor(sp, m, 64);
        const float s   = sp + b2v;
        const float h1v = lds[H1O + lane];
        const float mn  = fmaxf(am, s);
        const float sc  = __expf(am - mn);
        const float p   = __expf(s - mn);
        aZ = aZ*sc + p;
        aP = aP*sc + p*h1v;
        am = mn;
      }
    } else { // stage wave: prefetch next x tile, 8-iteration load->write skew
      if (it < TS - TT) {
        const int nbase = (tile+1)*TT;
        if ((tt & 15) == 0) {
          const float* src = xb + lane*TS + nbase + tt;
          wB[0] = ((const float4*)src)[0];
          wB[1] = ((const float4*)src)[1];
          wB[2] = ((const float4*)src)[2];
          wB[3] = ((const float4*)src)[3];
        } else if ((tt & 15) == 8) {
          const int dst = (xsel ? XT0 : XT1) + (tt-8)*64 + lane;
          #pragma unroll
          for (int q2=0;q2<4;q2++){
            lds[dst + (q2*4+0)*64] = wB[q2].x;
            lds[dst + (q2*4+1)*64] = wB[q2].y;
            lds[dst + (q2*4+2)*64] = wB[q2].z;
            lds[dst + (q2*4+3)*64] = wB[q2].w;
          }
        }
      }
    }
    __syncthreads();
    // ---------------- phase B ----------------
    if (isGate && g >= 128) {
      const bool act = (l==0) ? (it < TS) : (it >= 1 && it <= TS);
      if (act) {
        const int j   = g - 128;
        const int rzb = (l==0) ? RZ0 : RZ1;
        const int hbo = (l==0) ? H0O : H1O;
        const float r = lds[rzb + j];
        const float z = lds[rzb + 64 + j];
        const float n = tanhf_(xnk + r*hnk);
        const float hold = lds[hbo + j];
        lds[hbo + j] = n + z*(hold - n);   // (1-z)*n + z*h
      }
    }
    __syncthreads();
  }

  // ---------------- epilogue ----------------
  if (isAttn) {
    const float pooled = aP / aZ;
    float mu = pooled;
    #pragma unroll
    for (int m=1;m<64;m<<=1) mu += __shfl_xor(mu, m, 64);
    mu *= (1.0f/64.0f);
    const float d = pooled - mu;
    float var = d*d;
    #pragma unroll
    for (int m=1;m<64;m<<=1) var += __shfl_xor(var, m, 64);
    var *= (1.0f/64.0f);
    const float y = d * rsqrtf(var + 1e-5f) * ln_g[lane] + ln_b[lane];
    lds[SCRO + lane] = y;
  }
  __syncthreads();
  if (tid < 32) {
    const float* hw = head_w1 + tid*64;
    float acc = head_b1[tid];
    #pragma unroll
    for (int k=0;k<16;k++){
      const float4 w4 = ((const float4*)hw)[k];
      acc += w4.x*lds[SCRO+4*k+0] + w4.y*lds[SCRO+4*k+1]
           + w4.z*lds[SCRO+4*k+2] + w4.w*lds[SCRO+4*k+3];
    }
    const float u = 0.5f*acc*(1.0f + erff(acc*0.70710678118654752f)); // exact GELU
    lds[SCRO + 64 + tid] = u;
  }
  __syncthreads();
  if (tid < 8) {
    const float* hw = head_w2 + tid*32;
    float acc = head_b2[tid];
    #pragma unroll
    for (int k=0;k<8;k++){
      const float4 w4 = ((const float4*)hw)[k];
      acc += w4.x*lds[SCRO+64+4*k+0] + w4.y*lds[SCRO+64+4*k+1]
           + w4.z*lds[SCRO+64+4*k+2] + w4.w*lds[SCRO+64+4*k+3];
    }
    out[b*8 + tid] = acc;
  }
}

extern "C" void kernel_launch(void* const* d_in, const int* in_sizes, int n_in,
                              void* d_out, int out_size, void* d_ws, size_t ws_size,
                              hipStream_t stream) {
  (void)in_sizes; (void)n_in; (void)d_ws; (void)ws_size; (void)out_size;
  const float* x       = (const float*)d_in[0];
  const float* w_ih0   = (const float*)d_in[1];
  const float* w_hh0   = (const float*)d_in[2];
  const float* b_ih0   = (const float*)d_in[3];
  const float* b_hh0   = (const float*)d_in[4];
  const float* w_ih1   = (const float*)d_in[5];
  const float* w_hh1   = (const float*)d_in[6];
  const float* b_ih1   = (const float*)d_in[7];
  const float* b_hh1   = (const float*)d_in[8];
  const float* attn_w1 = (const float*)d_in[9];
  const float* attn_b1 = (const float*)d_in[10];
  const float* attn_w2 = (const float*)d_in[11];
  const float* attn_b2 = (const float*)d_in[12];
  const float* ln_g    = (const float*)d_in[13];
  const float* ln_b    = (const float*)d_in[14];
  const float* head_w1 = (const float*)d_in[15];
  const float* head_b1 = (const float*)d_in[16];
  const float* head_w2 = (const float*)d_in[17];
  const float* head_b2 = (const float*)d_in[18];
  hipLaunchKernelGGL(gru_attn_fused, dim3(256), dim3(512), 0, stream,
                     x, w_ih0, w_hh0, b_ih0, b_hh0, w_ih1, w_hh1, b_ih1, b_hh1,
                     attn_w1, attn_b1, attn_w2, attn_b2, ln_g, ln_b,
                     head_w1, head_b1, head_w2, head_b2, (float*)d_out);
}

// Round 2
// 2340.217 us; speedup vs baseline: 1.6217x; 1.6217x over previous
//
#include <hip/hip_runtime.h>
#include <math.h>

#define BB 256
#define CC 64
#define TS 2048
#define HH 64
#define TT 64

// LDS float offsets
#define XT0   0
#define XT1   4096
#define H0O   8192
#define H1O   8256
#define RZ0   8320
#define RZ1   8448
#define SPART 8576
#define SCRO  8584
#define LDSF  8684

__device__ __forceinline__ float sigmoidf_(float v){ return 1.0f/(1.0f+__expf(-v)); }
__device__ __forceinline__ float tanhf_(float v){
  v = fminf(15.0f, fmaxf(-15.0f, v));
  float e = __expf(2.0f*v);
  return (e-1.0f)/(e+1.0f);
}

// 15 waves = 960 threads:
//   waves 0-5  : layer-0 gates, half-rows (wave w6=wid: rows w6*32..+31; r=w6 0-1, z=2-3, n=4-5)
//   waves 6-11 : layer-1 gates, half-rows
//   waves 12-13: attention, half-rows (32 attn_w1 rows each)
//   wave 14    : x stage
// Each gate thread: 32 W_ih + 32 W_hh floats in VGPRs (64 total). Halves pair lane <-> lane^32.
__global__ __launch_bounds__(960, 2)
void gru_attn_fused(const float* __restrict__ x,
                    const float* __restrict__ w_ih0, const float* __restrict__ w_hh0,
                    const float* __restrict__ b_ih0, const float* __restrict__ b_hh0,
                    const float* __restrict__ w_ih1, const float* __restrict__ w_hh1,
                    const float* __restrict__ b_ih1, const float* __restrict__ b_hh1,
                    const float* __restrict__ attn_w1, const float* __restrict__ attn_b1,
                    const float* __restrict__ attn_w2, const float* __restrict__ attn_b2,
                    const float* __restrict__ ln_g, const float* __restrict__ ln_b,
                    const float* __restrict__ head_w1, const float* __restrict__ head_b1,
                    const float* __restrict__ head_w2, const float* __restrict__ head_b2,
                    float* __restrict__ out)
{
  __shared__ float lds[LDSF];
  const int tid  = threadIdx.x;
  const int b    = blockIdx.x;
  const int wid  = tid >> 6;
  const int lane = tid & 63;
  const int hoff = (lane >> 5) * 32;          // half offset in floats
  const bool isGate = (wid < 12);
  const bool isAttn = (wid == 12 || wid == 13);
  const int  l   = (wid < 6) ? 0 : 1;
  const int  w6  = isGate ? (wid - l*6) : 0;  // 0..5 within layer
  const int  g   = w6*32 + (lane & 31);       // gate row 0..191
  const float* xb = x + (size_t)b * CC * TS;

  float4 wA[8], wB[8];                        // 64 VGPRs of weights
  float bi = 0.f, bh = 0.f, w2j = 0.f, b2v = 0.f;

  if (isGate) {
    const float* wih = ((l==0) ? w_ih0 : w_ih1) + g*64 + hoff;
    const float* whh = ((l==0) ? w_hh0 : w_hh1) + g*64 + hoff;
    #pragma unroll
    for (int i=0;i<8;i++){ wA[i] = ((const float4*)wih)[i]; wB[i] = ((const float4*)whh)[i]; }
    bi = ((l==0) ? b_ih0 : b_ih1)[g];
    bh = ((l==0) ? b_hh0 : b_hh1)[g];
  } else if (isAttn) {
    const int o = (wid-12)*32 + (lane & 31);  // attn row 0..63
    const float* aw = attn_w1 + o*64 + hoff;
    #pragma unroll
    for (int i=0;i<8;i++){ wA[i] = ((const float4*)aw)[i]; }
    bi  = attn_b1[o];
    w2j = (lane < 32) ? attn_w2[o] : 0.f;     // count each row once in the reduce
    b2v = attn_b2[0];
  }

  // zero h0, h1, rz0, rz1 (contiguous 384 floats at H0O)
  if (tid < 384) lds[H0O + tid] = 0.f;
  if (tid == 384) lds[SPART] = 0.f;

  // stage x tile 0 (transposed: xT[tt][c]) using 512 threads
  if (tid < 512) {
    const int c0 = tid >> 3;
    const int q  = tid & 7;
    const int t0 = q*8;
    #pragma unroll
    for (int m=0;m<2;m++){
      float4 v = *(const float4*)(xb + c0*TS + t0 + m*4);
      lds[XT0 + (t0+m*4+0)*64 + c0] = v.x;
      lds[XT0 + (t0+m*4+1)*64 + c0] = v.y;
      lds[XT0 + (t0+m*4+2)*64 + c0] = v.z;
      lds[XT0 + (t0+m*4+3)*64 + c0] = v.w;
    }
  }
  __syncthreads();

  float am = -1e30f, aZ = 0.f, aP = 0.f;   // online softmax state (wave 12)
  float S12 = 0.f;                          // wave-12 partial score
  float h1v = 0.f;                          // h1[lane] snapshot (attn)
  float xnk = 0.f, hnk = 0.f;               // n-gate carries A->B
  float4 sv = make_float4(0.f,0.f,0.f,0.f); // stage pipeline

  // Skewed pipeline: iter it: L0@t=it, L1@t=it-1, attn@t=it-2
  #pragma unroll 1
  for (int it = 0; it < TS + 2; ++it) {
    const int tt   = it & (TT-1);
    const int tile = it >> 6;
    const int xsel = tile & 1;

    // ---------------- phase A ----------------
    if (isGate) {
      const bool act = (l==0) ? (it < TS) : (it >= 1 && it <= TS);
      if (act) {
        const float* iv; const float* hv;
        if (l==0) { iv = &lds[(xsel ? XT1 : XT0) + tt*64 + hoff]; hv = &lds[H0O + hoff]; }
        else      { iv = &lds[H0O + hoff];                        hv = &lds[H1O + hoff]; }
        float a0=0,a1=0,a2=0,a3=0, c0=0,c1=0,c2=0,c3=0;
        #pragma unroll
        for (int i=0;i<8;i++){
          const float4 vx = ((const float4*)iv)[i];
          const float4 vh = ((const float4*)hv)[i];
          a0 = fmaf(wA[i].x, vx.x, a0);
          a1 = fmaf(wA[i].y, vx.y, a1);
          a2 = fmaf(wA[i].z, vx.z, a2);
          a3 = fmaf(wA[i].w, vx.w, a3);
          c0 = fmaf(wB[i].x, vh.x, c0);
          c1 = fmaf(wB[i].y, vh.y, c1);
          c2 = fmaf(wB[i].z, vh.z, c2);
          c3 = fmaf(wB[i].w, vh.w, c3);
        }
        float ihp = (a0+a1)+(a2+a3);
        float hhp = (c0+c1)+(c2+c3);
        ihp += __shfl_xor(ihp, 32);
        hhp += __shfl_xor(hhp, 32);
        if (lane < 32) {
          const float ihd = bi + ihp;
          const float hhd = bh + hhp;
          if (w6 < 4) {
            lds[((l==0)?RZ0:RZ1) + w6*32 + lane] = sigmoidf_(ihd + hhd);  // r: 0-63, z: 64-127
          } else {
            xnk = ihd; hnk = hhd;   // n-gate: keep xn, hn separate
          }
        }
      }
    } else if (isAttn) {
      if (it >= 2) {
        const float* hv = &lds[H1O + hoff];
        float a0=0,a1=0,a2=0,a3=0;
        #pragma unroll
        for (int i=0;i<8;i++){
          const float4 vh = ((const float4*)hv)[i];
          a0 = fmaf(wA[i].x, vh.x, a0);
          a1 = fmaf(wA[i].y, vh.y, a1);
          a2 = fmaf(wA[i].z, vh.z, a2);
          a3 = fmaf(wA[i].w, vh.w, a3);
        }
        float ap = (a0+a1)+(a2+a3);
        ap += __shfl_xor(ap, 32);
        const float a = tanhf_(bi + ap);
        float sp = w2j * a;                 // lane>=32 contributes 0
        #pragma unroll
        for (int m=1;m<64;m<<=1) sp += __shfl_xor(sp, m, 64);
        if (wid == 13) { if (lane == 0) lds[SPART] = sp; }
        else           { S12 = sp; h1v = lds[H1O + lane]; }
      }
    } else { // wave 14: stage next x tile, float4 every 4 iterations
      if (it < TS - TT) {
        const int m = tt >> 2;
        if ((tt & 3) == 0) {
          sv = *(const float4*)(xb + lane*TS + (tile+1)*TT + m*4);
        } else if ((tt & 3) == 3) {
          const int dst = (xsel ? XT0 : XT1) + lane;
          lds[dst + (m*4+0)*64] = sv.x;
          lds[dst + (m*4+1)*64] = sv.y;
          lds[dst + (m*4+2)*64] = sv.z;
          lds[dst + (m*4+3)*64] = sv.w;
        }
      }
    }
    __syncthreads();
    // ---------------- phase B ----------------
    if (isGate && w6 >= 4 && lane < 32) {
      const bool act = (l==0) ? (it < TS) : (it >= 1 && it <= TS);
      if (act) {
        const int j   = (w6-4)*32 + lane;
        const int rzb = (l==0) ? RZ0 : RZ1;
        const int hbo = (l==0) ? H0O : H1O;
        const float r = lds[rzb + j];
        const float z = lds[rzb + 64 + j];
        const float n = tanhf_(xnk + r*hnk);
        const float hold = lds[hbo + j];
        lds[hbo + j] = n + z*(hold - n);   // (1-z)*n + z*h
      }
    } else if (wid == 12 && it >= 2) {
      const float s  = S12 + lds[SPART] + b2v;
      const float mn = fmaxf(am, s);
      const float sc = __expf(am - mn);
      const float p  = __expf(s - mn);
      aZ = aZ*sc + p;
      aP = aP*sc + p*h1v;
      am = mn;
    }
    __syncthreads();
  }

  // ---------------- epilogue ----------------
  if (wid == 12) {
    const float pooled = aP / aZ;
    float mu = pooled;
    #pragma unroll
    for (int m=1;m<64;m<<=1) mu += __shfl_xor(mu, m, 64);
    mu *= (1.0f/64.0f);
    const float d = pooled - mu;
    float var = d*d;
    #pragma unroll
    for (int m=1;m<64;m<<=1) var += __shfl_xor(var, m, 64);
    var *= (1.0f/64.0f);
    const float y = d * rsqrtf(var + 1e-5f) * ln_g[lane] + ln_b[lane];
    lds[SCRO + lane] = y;
  }
  __syncthreads();
  if (tid < 32) {
    const float* hw = head_w1 + tid*64;
    float acc = head_b1[tid];
    #pragma unroll
    for (int k=0;k<16;k++){
      const float4 w4 = ((const float4*)hw)[k];
      acc += w4.x*lds[SCRO+4*k+0] + w4.y*lds[SCRO+4*k+1]
           + w4.z*lds[SCRO+4*k+2] + w4.w*lds[SCRO+4*k+3];
    }
    const float u = 0.5f*acc*(1.0f + erff(acc*0.70710678118654752f)); // exact GELU
    lds[SCRO + 64 + tid] = u;
  }
  __syncthreads();
  if (tid < 8) {
    const float* hw = head_w2 + tid*32;
    float acc = head_b2[tid];
    #pragma unroll
    for (int k=0;k<8;k++){
      const float4 w4 = ((const float4*)hw)[k];
      acc += w4.x*lds[SCRO+64+4*k+0] + w4.y*lds[SCRO+64+4*k+1]
           + w4.z*lds[SCRO+64+4*k+2] + w4.w*lds[SCRO+64+4*k+3];
    }
    out[b*8 + tid] = acc;
  }
}

extern "C" void kernel_launch(void* const* d_in, const int* in_sizes, int n_in,
                              void* d_out, int out_size, void* d_ws, size_t ws_size,
                              hipStream_t stream) {
  (void)in_sizes; (void)n_in; (void)d_ws; (void)ws_size; (void)out_size;
  const float* x       = (const float*)d_in[0];
  const float* w_ih0   = (const float*)d_in[1];
  const float* w_hh0   = (const float*)d_in[2];
  const float* b_ih0   = (const float*)d_in[3];
  const float* b_hh0   = (const float*)d_in[4];
  const float* w_ih1   = (const float*)d_in[5];
  const float* w_hh1   = (const float*)d_in[6];
  const float* b_ih1   = (const float*)d_in[7];
  const float* b_hh1   = (const float*)d_in[8];
  const float* attn_w1 = (const float*)d_in[9];
  const float* attn_b1 = (const float*)d_in[10];
  const float* attn_w2 = (const float*)d_in[11];
  const float* attn_b2 = (const float*)d_in[12];
  const float* ln_g    = (const float*)d_in[13];
  const float* ln_b    = (const float*)d_in[14];
  const float* head_w1 = (const float*)d_in[15];
  const float* head_b1 = (const float*)d_in[16];
  const float* head_w2 = (const float*)d_in[17];
  const float* head_b2 = (const float*)d_in[18];
  hipLaunchKernelGGL(gru_attn_fused, dim3(256), dim3(960), 0, stream,
                     x, w_ih0, w_hh0, b_ih0, b_hh0, w_ih1, w_hh1, b_ih1, b_hh1,
                     attn_w1, attn_b1, attn_w2, attn_b2, ln_g, ln_b,
                     head_w1, head_b1, head_w2, head_b2, (float*)d_out);
}